// Round 8
// baseline (227.448 us; speedup 1.0000x reference)
//
#include <hip/hip_runtime.h>

#define HD 256
#define LN_EPS 1e-5f
#define DEG_EPS 1e-6f
#define CAP 64

typedef __attribute__((ext_vector_type(8))) short short8;
typedef __attribute__((ext_vector_type(4))) short s16x4;
typedef __attribute__((ext_vector_type(4))) float f32x4;

__device__ inline unsigned short f2bf(float f) {
    union { float f; unsigned int u; } v; v.f = f;
    unsigned int r = v.u + 0x7FFFu + ((v.u >> 16) & 1u);
    return (unsigned short)(r >> 16);
}
__device__ inline float bf2f(unsigned short h) {
    union { unsigned int u; float f; } v; v.u = ((unsigned int)h) << 16;
    return v.f;
}

// Convert weight matrices to bf16 once per launch (deterministic, tiny).
__global__ void prep_kernel(const float* __restrict__ msg_W,
                            const float* __restrict__ upd_W,
                            unsigned short* __restrict__ w1b,
                            unsigned short* __restrict__ w2b,
                            float* __restrict__ ucol) {
    int t = blockIdx.x * blockDim.x + threadIdx.x;
    if (t < 256 * 256) {
        w1b[t] = f2bf(msg_W[t]);
        int j = t >> 8, k = t & 255;
        w2b[t] = f2bf(upd_W[j * 257 + k]);
        if (k == 0) ucol[j] = upd_W[j * 257 + 256];
    }
}

// Bucket edges by dst: counts[] = degree, eidx[d*CAP + p] = src ids.
__global__ __launch_bounds__(256) void fill_kernel(
    const int* __restrict__ src, const int* __restrict__ dst,
    int* __restrict__ counts, int* __restrict__ eidx, int E) {
    int e = blockIdx.x * 256 + threadIdx.x;
    if (e >= E) return;
    int d = dst[e];
    int p = atomicAdd(&counts[d], 1);
    if (p < CAP) eidx[d * CAP + p] = src[e];
}

// y = bf16(x_var @ W1^T). Dense streaming GEMM, weight-stationary:
// 512 thr = 8 waves, wave w holds W1 rows [w*32, w*32+32) (64 VGPR).
// Grid-stride over 16-row tiles; LDS transpose -> coalesced bf16 stores.
#define CX 264
__global__ __launch_bounds__(512) void xform_kernel(
    const float* __restrict__ x_var, const unsigned short* __restrict__ w1b,
    unsigned short* __restrict__ y, int n_var, int ntiles) {

    __shared__ unsigned short sT[2][16 * CX];
    const int tid = threadIdx.x, w = tid >> 6, lane = tid & 63;
    const int lr = lane & 15, lg = lane >> 4;
    const int jb = w * 32;

    short8 bfr[2][8];
#pragma unroll
    for (int jt = 0; jt < 2; ++jt)
#pragma unroll
        for (int ks = 0; ks < 8; ++ks)
            bfr[jt][ks] = *(const short8*)(w1b + (jb + jt * 16 + lr) * HD + lg * 8 + ks * 32);

    int buf = 0;
#pragma unroll 1
    for (int rt = blockIdx.x; rt < ntiles; rt += gridDim.x) {
        int r0 = rt * 16;
        int arc = min(r0 + lr, n_var - 1);
        const float* ap = x_var + (long)arc * HD + lg * 8;
        short8 af[8];
#pragma unroll
        for (int ks = 0; ks < 8; ++ks) {
            float4 u0 = *(const float4*)(ap + ks * 32);
            float4 u1 = *(const float4*)(ap + ks * 32 + 4);
            short8 f;
            f[0] = (short)f2bf(u0.x); f[1] = (short)f2bf(u0.y);
            f[2] = (short)f2bf(u0.z); f[3] = (short)f2bf(u0.w);
            f[4] = (short)f2bf(u1.x); f[5] = (short)f2bf(u1.y);
            f[6] = (short)f2bf(u1.z); f[7] = (short)f2bf(u1.w);
            af[ks] = f;
        }
        f32x4 acc[2] = {{0.f,0.f,0.f,0.f},{0.f,0.f,0.f,0.f}};
#pragma unroll
        for (int ks = 0; ks < 8; ++ks)
#pragma unroll
            for (int jt = 0; jt < 2; ++jt)
                acc[jt] = __builtin_amdgcn_mfma_f32_16x16x32_bf16(af[ks], bfr[jt][ks], acc[jt], 0, 0, 0);
#pragma unroll
        for (int jt = 0; jt < 2; ++jt)
#pragma unroll
            for (int q = 0; q < 4; ++q)
                sT[buf][(lg * 4 + q) * CX + jb + jt * 16 + lr] = f2bf(acc[jt][q]);
        __syncthreads();
        {
            int row = tid >> 5, seg = tid & 31;   // 16 rows x 32 segs of 8 cols
            int grow = r0 + row;
            if (grow < n_var) {
                short8 v = *(const short8*)(&sT[buf][row * CX + seg * 8]);
                *(short8*)(y + (long)grow * HD + seg * 8) = v;
            }
        }
        buf ^= 1;
    }
}

// M[c] = bf16( (sum_e y[src_e]) / (deg+eps) + (deg/(deg+eps))*msg_b ).
// One wave per constraint; bf16 rows (512B) halve gather bytes; batch-8
// keeps 8 loads in flight.
__global__ __launch_bounds__(256) void gather2_kernel(
    const unsigned short* __restrict__ y, const int* __restrict__ counts,
    const int* __restrict__ eidx, const float* __restrict__ msg_b,
    unsigned short* __restrict__ M, int num_con) {
    int row  = blockIdx.x * 4 + (threadIdx.x >> 6);
    int lane = threadIdx.x & 63;
    if (row >= num_con) return;
    int cnt = counts[row];
    int cgo = min(cnt, CAP);
    int sid = (lane < cgo) ? eidx[row * CAP + lane] : 0;
    float a0 = 0.f, a1 = 0.f, a2 = 0.f, a3 = 0.f;
#pragma unroll 1
    for (int i = 0; i < cgo; i += 8) {
        int s[8];
#pragma unroll
        for (int u = 0; u < 8; ++u) s[u] = __shfl(sid, i + u, 64);
        s16x4 v[8];
#pragma unroll
        for (int u = 0; u < 8; ++u)
            v[u] = *(const s16x4*)(y + (long)s[u] * HD + lane * 4);
#pragma unroll
        for (int u = 0; u < 8; ++u) {
            float wg = (i + u < cgo) ? 1.f : 0.f;
            a0 += bf2f((unsigned short)v[u][0]) * wg;
            a1 += bf2f((unsigned short)v[u][1]) * wg;
            a2 += bf2f((unsigned short)v[u][2]) * wg;
            a3 += bf2f((unsigned short)v[u][3]) * wg;
        }
    }
    float sc = 1.0f / ((float)cnt + DEG_EPS);
    float tc = (float)cnt * sc;
    float4 b4 = *(const float4*)(msg_b + lane * 4);
    s16x4 o;
    o[0] = (short)f2bf(a0 * sc + tc * b4.x);
    o[1] = (short)f2bf(a1 * sc + tc * b4.y);
    o[2] = (short)f2bf(a2 * sc + tc * b4.z);
    o[3] = (short)f2bf(a3 * sc + tc * b4.w);
    *(s16x4*)(M + (long)row * HD + lane * 4) = o;
}

// out = LN(relu(M @ W2^T + ucol*clue + b2)) * ln_w + ln_b.
// Same weight-stationary 32-col-wave structure; LN via LDS + shfl_xor.
#define C2 264
__global__ __launch_bounds__(512) void g2_kernel(
    const unsigned short* __restrict__ M, const float* __restrict__ clue,
    const unsigned short* __restrict__ w2b, const float* __restrict__ ucol,
    const float* __restrict__ upd_b,
    const float* __restrict__ ln_w, const float* __restrict__ ln_b,
    float* __restrict__ out, int num_con, int ntiles) {

    __shared__ float sZ[2][16 * C2];
    const int tid = threadIdx.x, w = tid >> 6, lane = tid & 63;
    const int lr = lane & 15, lg = lane >> 4;
    const int jb = w * 32;

    short8 bfr[2][8];
#pragma unroll
    for (int jt = 0; jt < 2; ++jt)
#pragma unroll
        for (int ks = 0; ks < 8; ++ks)
            bfr[jt][ks] = *(const short8*)(w2b + (jb + jt * 16 + lr) * HD + lg * 8 + ks * 32);
    float uc[2], b2[2];
#pragma unroll
    for (int jt = 0; jt < 2; ++jt) {
        uc[jt] = ucol[jb + jt * 16 + lr];
        b2[jt] = upd_b[jb + jt * 16 + lr];
    }
    const int seg = tid & 31;                  // store-phase: 8 cols per thread
    f32x4 lw0 = *(const f32x4*)(ln_w + seg * 8);
    f32x4 lw1 = *(const f32x4*)(ln_w + seg * 8 + 4);
    f32x4 lb0 = *(const f32x4*)(ln_b + seg * 8);
    f32x4 lb1 = *(const f32x4*)(ln_b + seg * 8 + 4);

    int buf = 0;
#pragma unroll 1
    for (int rt = blockIdx.x; rt < ntiles; rt += gridDim.x) {
        int r0 = rt * 16;
        int arc = min(r0 + lr, num_con - 1);
        const unsigned short* ap = M + (long)arc * HD + lg * 8;
        short8 af[8];
#pragma unroll
        for (int ks = 0; ks < 8; ++ks) af[ks] = *(const short8*)(ap + ks * 32);

        f32x4 acc[2] = {{0.f,0.f,0.f,0.f},{0.f,0.f,0.f,0.f}};
#pragma unroll
        for (int ks = 0; ks < 8; ++ks)
#pragma unroll
            for (int jt = 0; jt < 2; ++jt)
                acc[jt] = __builtin_amdgcn_mfma_f32_16x16x32_bf16(af[ks], bfr[jt][ks], acc[jt], 0, 0, 0);

        float cl[4];
#pragma unroll
        for (int q = 0; q < 4; ++q)
            cl[q] = clue[min(r0 + lg * 4 + q, num_con - 1)];
#pragma unroll
        for (int jt = 0; jt < 2; ++jt)
#pragma unroll
            for (int q = 0; q < 4; ++q) {
                float z = fmaxf(acc[jt][q] + uc[jt] * cl[q] + b2[jt], 0.0f);
                sZ[buf][(lg * 4 + q) * C2 + jb + jt * 16 + lr] = z;
            }
        __syncthreads();
        {
            int row = tid >> 5;                 // 16 rows x 32 segs
            const float* zp = &sZ[buf][row * C2 + seg * 8];
            f32x4 z0 = *(const f32x4*)(zp);
            f32x4 z1 = *(const f32x4*)(zp + 4);
            float s = 0.f, s2 = 0.f;
#pragma unroll
            for (int e = 0; e < 4; ++e) {
                s += z0[e] + z1[e];
                s2 += z0[e] * z0[e] + z1[e] * z1[e];
            }
#pragma unroll
            for (int m = 1; m < 32; m <<= 1) {  // reduce across the row's 32 thr
                s  += __shfl_xor(s,  m, 64);
                s2 += __shfl_xor(s2, m, 64);
            }
            float mu = s * (1.0f / HD);
            float var = s2 * (1.0f / HD) - mu * mu;
            float rs = rsqrtf(var + LN_EPS);
            int grow = r0 + row;
            if (grow < num_con) {
                float* gp = out + (long)grow * HD + seg * 8;
                f32x4 o0, o1;
#pragma unroll
                for (int e = 0; e < 4; ++e) {
                    o0[e] = (z0[e] - mu) * rs * lw0[e] + lb0[e];
                    o1[e] = (z1[e] - mu) * rs * lw1[e] + lb1[e];
                }
                *(f32x4*)gp = o0;
                *(f32x4*)(gp + 4) = o1;
            }
        }
        buf ^= 1;
    }
}

extern "C" void kernel_launch(void* const* d_in, const int* in_sizes, int n_in,
                              void* d_out, int out_size, void* d_ws, size_t ws_size,
                              hipStream_t stream) {
    const float* x_var = (const float*)d_in[0];
    const int*   src   = (const int*)d_in[1];
    const int*   dst   = (const int*)d_in[2];
    const float* clue  = (const float*)d_in[3];
    // d_in[4] = num_con scalar (derived from out_size instead)
    const float* msg_W = (const float*)d_in[5];
    const float* msg_b = (const float*)d_in[6];
    const float* upd_W = (const float*)d_in[7];
    const float* upd_b = (const float*)d_in[8];
    const float* ln_w  = (const float*)d_in[9];
    const float* ln_b  = (const float*)d_in[10];

    int E = in_sizes[1];
    int n_var = in_sizes[0] / HD;
    int num_con = out_size / HD;
    int ntiles_v = (n_var + 15) / 16;
    int ntiles_c = (num_con + 15) / 16;

    char* ws = (char*)d_ws;
    int* counts = (int*)ws;                               // num_con ints
    int* eidx   = (int*)(ws + (((size_t)num_con * 4 + 255) & ~(size_t)255));
    char* after = (char*)(eidx + (size_t)num_con * CAP);  // num_con*CAP ints
    size_t yoff = ((size_t)(after - ws) + 255) & ~(size_t)255;
    unsigned short* yv = (unsigned short*)(ws + yoff);    // n_var*256 bf16
    size_t moff = (yoff + (size_t)n_var * HD * 2 + 255) & ~(size_t)255;
    unsigned short* M = (unsigned short*)(ws + moff);     // num_con*256 bf16
    size_t woff = (moff + (size_t)num_con * HD * 2 + 255) & ~(size_t)255;
    unsigned short* w1b = (unsigned short*)(ws + woff);
    unsigned short* w2b = w1b + 256 * 256;
    float* ucol = (float*)(w2b + 256 * 256);

    (void)hipMemsetAsync(counts, 0, (size_t)num_con * 4, stream);

    prep_kernel<<<256, 256, 0, stream>>>(msg_W, upd_W, w1b, w2b, ucol);

    fill_kernel<<<(E + 255) / 256, 256, 0, stream>>>(src, dst, counts, eidx, E);

    xform_kernel<<<1024, 512, 0, stream>>>(x_var, w1b, yv, n_var, ntiles_v);

    gather2_kernel<<<(num_con + 3) / 4, 256, 0, stream>>>(
        yv, counts, eidx, msg_b, M, num_con);

    g2_kernel<<<1024, 512, 0, stream>>>(M, clue, w2b, ucol, upd_b, ln_w, ln_b,
                                        (float*)d_out, num_con, ntiles_c);
}

// Round 9
// 159.800 us; speedup vs baseline: 1.4233x; 1.4233x over previous
//
#include <hip/hip_runtime.h>

#define HD 256
#define LN_EPS 1e-5f
#define DEG_EPS 1e-6f
#define CAP 64
#define CM 264
#define CZ 264

typedef __attribute__((ext_vector_type(8))) short short8;
typedef __attribute__((ext_vector_type(4))) short s16x4;
typedef __attribute__((ext_vector_type(4))) float f32x4;

__device__ inline unsigned short f2bf(float f) {
    union { float f; unsigned int u; } v; v.f = f;
    unsigned int r = v.u + 0x7FFFu + ((v.u >> 16) & 1u);
    return (unsigned short)(r >> 16);
}
__device__ inline float bf2f(unsigned short h) {
    union { unsigned int u; float f; } v; v.u = ((unsigned int)h) << 16;
    return v.f;
}

// Convert weight matrices to bf16 once per launch (deterministic, tiny).
__global__ void prep_kernel(const float* __restrict__ msg_W,
                            const float* __restrict__ upd_W,
                            unsigned short* __restrict__ w1b,
                            unsigned short* __restrict__ w2b,
                            float* __restrict__ ucol) {
    int t = blockIdx.x * blockDim.x + threadIdx.x;
    if (t < 256 * 256) {
        w1b[t] = f2bf(msg_W[t]);
        int j = t >> 8, k = t & 255;
        w2b[t] = f2bf(upd_W[j * 257 + k]);
        if (k == 0) ucol[j] = upd_W[j * 257 + 256];
    }
}

// Bucket edges by dst: counts[] = degree, eidx[d*CAP + p] = src ids.
__global__ __launch_bounds__(256) void fill_kernel(
    const int* __restrict__ src, const int* __restrict__ dst,
    int* __restrict__ counts, int* __restrict__ eidx, int E) {
    int e = blockIdx.x * 256 + threadIdx.x;
    if (e >= E) return;
    int d = dst[e];
    int p = atomicAdd(&counts[d], 1);
    if (p < CAP) eidx[d * CAP + p] = src[e];
}

// x fp32 -> bf16 (streaming cast). Makes the gather working set 51MB
// (L3-resident) and halves gather bytes.
__global__ __launch_bounds__(256) void xcast_kernel(
    const float* __restrict__ x, unsigned short* __restrict__ xb, long n) {
    long i = ((long)blockIdx.x * 256 + threadIdx.x) * 8;
    if (i + 8 <= n) {
        float4 u0 = *(const float4*)(x + i);
        float4 u1 = *(const float4*)(x + i + 4);
        short8 o;
        o[0] = (short)f2bf(u0.x); o[1] = (short)f2bf(u0.y);
        o[2] = (short)f2bf(u0.z); o[3] = (short)f2bf(u0.w);
        o[4] = (short)f2bf(u1.x); o[5] = (short)f2bf(u1.y);
        o[6] = (short)f2bf(u1.z); o[7] = (short)f2bf(u1.w);
        *(short8*)(xb + i) = o;
    } else {
        for (; i < n; ++i) xb[i] = f2bf(x[i]);
    }
}

// One wave per constraint row; 4 rows per 256-thr block; batch-8 keeps
// 8 row-loads in flight. Reads bf16 x rows (512B granules, L3-resident).
// Emits pre-scaled bf16 agg [num_con][256] (no bias here).
__global__ __launch_bounds__(256) void gather_kernel(
    const unsigned short* __restrict__ xb, const int* __restrict__ counts,
    const int* __restrict__ eidx, unsigned short* __restrict__ agg,
    int num_con) {
    int row  = blockIdx.x * 4 + (threadIdx.x >> 6);
    int lane = threadIdx.x & 63;
    if (row >= num_con) return;
    int cnt = counts[row];
    int cgo = min(cnt, CAP);
    int sid = (lane < cgo) ? eidx[row * CAP + lane] : 0;
    float a0 = 0.f, a1 = 0.f, a2 = 0.f, a3 = 0.f;
#pragma unroll 1
    for (int i = 0; i < cgo; i += 8) {
        int s[8];
#pragma unroll
        for (int u = 0; u < 8; ++u) s[u] = __shfl(sid, i + u, 64);
        s16x4 v[8];
#pragma unroll
        for (int u = 0; u < 8; ++u)
            v[u] = *(const s16x4*)(xb + (long)s[u] * HD + lane * 4);
#pragma unroll
        for (int u = 0; u < 8; ++u) {
            float wg = (i + u < cgo) ? 1.f : 0.f;
            a0 = fmaf(bf2f((unsigned short)v[u][0]), wg, a0);
            a1 = fmaf(bf2f((unsigned short)v[u][1]), wg, a1);
            a2 = fmaf(bf2f((unsigned short)v[u][2]), wg, a2);
            a3 = fmaf(bf2f((unsigned short)v[u][3]), wg, a3);
        }
    }
    float sc = 1.0f / ((float)cnt + DEG_EPS);
    s16x4 o;
    o[0] = (short)f2bf(a0 * sc); o[1] = (short)f2bf(a1 * sc);
    o[2] = (short)f2bf(a2 * sc); o[3] = (short)f2bf(a3 * sc);
    *(s16x4*)(agg + (long)row * HD + lane * 4) = o;
}

// Merged GEMM1+GEMM2, weight-stationary: 512 thr = 8 waves; wave w holds
// the 32-col strips of BOTH W1 and W2 (128 VGPR). Per 16-row tile:
// GEMM1(agg) -> M bf16 in LDS -> barrier -> GEMM2(M) + clue/bias/ReLU
// -> z fp32 in LDS -> barrier -> LN + coalesced store. Single-buffered
// LDS is safe: 2 barriers/iter separate all cross-iteration hazards.
__global__ __launch_bounds__(512) void gfused_kernel(
    const unsigned short* __restrict__ agg, const int* __restrict__ counts,
    const float* __restrict__ clue,
    const unsigned short* __restrict__ w1b, const float* __restrict__ msg_b,
    const unsigned short* __restrict__ w2b, const float* __restrict__ ucol,
    const float* __restrict__ upd_b,
    const float* __restrict__ ln_w, const float* __restrict__ ln_b,
    float* __restrict__ out, int num_con, int ntiles) {

    __shared__ unsigned short sM[16 * CM];
    __shared__ float sZ[16 * CZ];
    const int tid = threadIdx.x, w = tid >> 6, lane = tid & 63;
    const int lr = lane & 15, lg = lane >> 4;
    const int jb = w * 32;

    short8 b1r[2][8], b2r[2][8];
#pragma unroll
    for (int jt = 0; jt < 2; ++jt)
#pragma unroll
        for (int ks = 0; ks < 8; ++ks) {
            b1r[jt][ks] = *(const short8*)(w1b + (jb + jt * 16 + lr) * HD + lg * 8 + ks * 32);
            b2r[jt][ks] = *(const short8*)(w2b + (jb + jt * 16 + lr) * HD + lg * 8 + ks * 32);
        }
    float bj[2], uc[2], ub[2];
#pragma unroll
    for (int jt = 0; jt < 2; ++jt) {
        bj[jt] = msg_b[jb + jt * 16 + lr];
        uc[jt] = ucol[jb + jt * 16 + lr];
        ub[jt] = upd_b[jb + jt * 16 + lr];
    }
    const int seg = tid & 31;                  // store-phase: 8 cols/thread
    f32x4 lw0 = *(const f32x4*)(ln_w + seg * 8);
    f32x4 lw1 = *(const f32x4*)(ln_w + seg * 8 + 4);
    f32x4 lb0 = *(const f32x4*)(ln_b + seg * 8);
    f32x4 lb1 = *(const f32x4*)(ln_b + seg * 8 + 4);

#pragma unroll 1
    for (int rt = blockIdx.x; rt < ntiles; rt += gridDim.x) {
        int r0 = rt * 16;
        int arc = min(r0 + lr, num_con - 1);
        const unsigned short* ap = agg + (long)arc * HD + lg * 8;
        short8 af[8];
#pragma unroll
        for (int ks = 0; ks < 8; ++ks) af[ks] = *(const short8*)(ap + ks * 32);

        // ---- GEMM1 ----
        f32x4 acc1[2] = {{0.f,0.f,0.f,0.f},{0.f,0.f,0.f,0.f}};
#pragma unroll
        for (int ks = 0; ks < 8; ++ks)
#pragma unroll
            for (int jt = 0; jt < 2; ++jt)
                acc1[jt] = __builtin_amdgcn_mfma_f32_16x16x32_bf16(af[ks], b1r[jt][ks], acc1[jt], 0, 0, 0);

        float trow[4];
#pragma unroll
        for (int q = 0; q < 4; ++q) {
            int rr = r0 + lg * 4 + q;
            float dvq = (rr < num_con) ? (float)counts[rr] : 0.f;
            trow[q] = dvq / (dvq + DEG_EPS);
        }
#pragma unroll
        for (int jt = 0; jt < 2; ++jt)
#pragma unroll
            for (int q = 0; q < 4; ++q) {
                float m = acc1[jt][q] + trow[q] * bj[jt];
                sM[(lg * 4 + q) * CM + jb + jt * 16 + lr] = f2bf(m);
            }
        __syncthreads();

        // ---- GEMM2 on M from LDS ----
        short8 a2[8];
#pragma unroll
        for (int ks = 0; ks < 8; ++ks)
            a2[ks] = *(const short8*)(&sM[lr * CM + lg * 8 + ks * 32]);

        f32x4 acc2[2] = {{0.f,0.f,0.f,0.f},{0.f,0.f,0.f,0.f}};
#pragma unroll
        for (int ks = 0; ks < 8; ++ks)
#pragma unroll
            for (int jt = 0; jt < 2; ++jt)
                acc2[jt] = __builtin_amdgcn_mfma_f32_16x16x32_bf16(a2[ks], b2r[jt][ks], acc2[jt], 0, 0, 0);

        float cl[4];
#pragma unroll
        for (int q = 0; q < 4; ++q)
            cl[q] = clue[min(r0 + lg * 4 + q, num_con - 1)];
#pragma unroll
        for (int jt = 0; jt < 2; ++jt)
#pragma unroll
            for (int q = 0; q < 4; ++q) {
                float z = fmaxf(acc2[jt][q] + uc[jt] * cl[q] + ub[jt], 0.0f);
                sZ[(lg * 4 + q) * CZ + jb + jt * 16 + lr] = z;
            }
        __syncthreads();

        // ---- LN + coalesced store (row = tid>>5, 32 thr/row) ----
        {
            int row = tid >> 5;
            const float* zp = &sZ[row * CZ + seg * 8];
            f32x4 z0 = *(const f32x4*)(zp);
            f32x4 z1 = *(const f32x4*)(zp + 4);
            float s = 0.f, s2 = 0.f;
#pragma unroll
            for (int e = 0; e < 4; ++e) {
                s += z0[e] + z1[e];
                s2 += z0[e] * z0[e] + z1[e] * z1[e];
            }
#pragma unroll
            for (int m = 1; m < 32; m <<= 1) {
                s  += __shfl_xor(s,  m, 64);
                s2 += __shfl_xor(s2, m, 64);
            }
            float mu = s * (1.0f / HD);
            float var = s2 * (1.0f / HD) - mu * mu;
            float rs = rsqrtf(var + LN_EPS);
            int grow = r0 + row;
            if (grow < num_con) {
                float* gp = out + (long)grow * HD + seg * 8;
                f32x4 o0, o1;
#pragma unroll
                for (int e = 0; e < 4; ++e) {
                    o0[e] = (z0[e] - mu) * rs * lw0[e] + lb0[e];
                    o1[e] = (z1[e] - mu) * rs * lw1[e] + lb1[e];
                }
                *(f32x4*)gp = o0;
                *(f32x4*)(gp + 4) = o1;
            }
        }
    }
}

extern "C" void kernel_launch(void* const* d_in, const int* in_sizes, int n_in,
                              void* d_out, int out_size, void* d_ws, size_t ws_size,
                              hipStream_t stream) {
    const float* x_var = (const float*)d_in[0];
    const int*   src   = (const int*)d_in[1];
    const int*   dst   = (const int*)d_in[2];
    const float* clue  = (const float*)d_in[3];
    // d_in[4] = num_con scalar (derived from out_size instead)
    const float* msg_W = (const float*)d_in[5];
    const float* msg_b = (const float*)d_in[6];
    const float* upd_W = (const float*)d_in[7];
    const float* upd_b = (const float*)d_in[8];
    const float* ln_w  = (const float*)d_in[9];
    const float* ln_b  = (const float*)d_in[10];

    int E = in_sizes[1];
    long n_x = in_sizes[0];
    int n_var = (int)(n_x / HD);
    int num_con = out_size / HD;
    int ntiles = (num_con + 15) / 16;

    char* ws = (char*)d_ws;
    int* counts = (int*)ws;                               // num_con ints
    int* eidx   = (int*)(ws + (((size_t)num_con * 4 + 255) & ~(size_t)255));
    char* after = (char*)(eidx + (size_t)num_con * CAP);  // num_con*CAP ints
    size_t xoff = ((size_t)(after - ws) + 255) & ~(size_t)255;
    unsigned short* xb = (unsigned short*)(ws + xoff);    // n_var*256 bf16
    size_t aoff = (xoff + (size_t)n_var * HD * 2 + 255) & ~(size_t)255;
    unsigned short* agg = (unsigned short*)(ws + aoff);   // num_con*256 bf16
    size_t woff = (aoff + (size_t)num_con * HD * 2 + 255) & ~(size_t)255;
    unsigned short* w1b = (unsigned short*)(ws + woff);
    unsigned short* w2b = w1b + 256 * 256;
    float* ucol = (float*)(w2b + 256 * 256);

    (void)hipMemsetAsync(counts, 0, (size_t)num_con * 4, stream);

    prep_kernel<<<256, 256, 0, stream>>>(msg_W, upd_W, w1b, w2b, ucol);

    fill_kernel<<<(E + 255) / 256, 256, 0, stream>>>(src, dst, counts, eidx, E);

    xcast_kernel<<<(int)((n_x / 8 + 255) / 256), 256, 0, stream>>>(x_var, xb, n_x);

    gather_kernel<<<(num_con + 3) / 4, 256, 0, stream>>>(
        xb, counts, eidx, agg, num_con);

    gfused_kernel<<<1024, 512, 0, stream>>>(
        agg, counts, clue, w1b, msg_b, w2b, ucol, upd_b, ln_w, ln_b,
        (float*)d_out, num_con, ntiles);
}